// Round 6
// baseline (1050.717 us; speedup 1.0000x reference)
//
#include <hip/hip_runtime.h>

typedef __attribute__((ext_vector_type(8))) __bf16 bf16x8;
typedef __attribute__((ext_vector_type(8))) short short8;
typedef __attribute__((ext_vector_type(4))) float f32x4;

__device__ __forceinline__ unsigned short f2bf(float f) {
    union { float f; unsigned int i; } c; c.f = f;
    unsigned int r = c.i + 0x7fffu + ((c.i >> 16) & 1u);  // round-nearest-even
    return (unsigned short)(r >> 16);
}

#define DIM 1024
#define NSEQ 4096
#define NH 16
#define HD 64

// ---------------------------------------------------------------------------
// GEMM: C[8192 x N] = A[8192 x 1024] * B[1024 x N] + bias
// A fp32 (bf16-rounded at LDS staging), B/bias fp32.
// MODE 0: scatter bf16 to Q/K/V [B,H,N,64] (out0/1/2).
// MODE 1: fp32 store to outf [8192 x 1024].
// 64x64 tile / 256 threads; wave = 32x32 quadrant; K-step 32.
// ---------------------------------------------------------------------------
template<int LDB, int MODE>
__global__ __launch_bounds__(256)
void gemm_kernel(const float* __restrict__ A,
                 const float* __restrict__ B,
                 const float* __restrict__ bias,
                 unsigned short* __restrict__ out0,
                 unsigned short* __restrict__ out1,
                 unsigned short* __restrict__ out2,
                 float* __restrict__ outf)
{
    __shared__ __align__(16) unsigned short As[64][32];   // [m][k] bf16
    __shared__ __align__(16) unsigned short Bs[64][32];   // [n][k] bf16 (B transposed)
    const int t    = threadIdx.x;
    const int m0   = blockIdx.x * 64;
    const int n0   = blockIdx.y * 64;
    const int lane = t & 63;
    const int wv   = t >> 6;
    const int l15  = lane & 15;
    const int quad = lane >> 4;
    const int wm   = (wv >> 1) * 32;
    const int wn   = (wv & 1) * 32;
    const int ar   = t >> 2, ac = (t & 3) * 8;   // A stage: 64 rows x 32 k
    const int br   = t >> 3, bc = (t & 7) * 8;   // B stage: 32 k x 64 n

    f32x4 acc[2][2] = {};

    for (int kt = 0; kt < 1024; kt += 32) {
        float4 a0 = *(const float4*)(A + (size_t)(m0 + ar) * 1024 + kt + ac);
        float4 a1 = *(const float4*)(A + (size_t)(m0 + ar) * 1024 + kt + ac + 4);
        float4 b0 = *(const float4*)(B + (size_t)(kt + br) * LDB + n0 + bc);
        float4 b1 = *(const float4*)(B + (size_t)(kt + br) * LDB + n0 + bc + 4);

        __syncthreads();                       // previous iteration's LDS reads done
        As[ar][ac + 0] = f2bf(a0.x); As[ar][ac + 1] = f2bf(a0.y);
        As[ar][ac + 2] = f2bf(a0.z); As[ar][ac + 3] = f2bf(a0.w);
        As[ar][ac + 4] = f2bf(a1.x); As[ar][ac + 5] = f2bf(a1.y);
        As[ar][ac + 6] = f2bf(a1.z); As[ar][ac + 7] = f2bf(a1.w);
        Bs[bc + 0][br] = f2bf(b0.x); Bs[bc + 1][br] = f2bf(b0.y);
        Bs[bc + 2][br] = f2bf(b0.z); Bs[bc + 3][br] = f2bf(b0.w);
        Bs[bc + 4][br] = f2bf(b1.x); Bs[bc + 5][br] = f2bf(b1.y);
        Bs[bc + 6][br] = f2bf(b1.z); Bs[bc + 7][br] = f2bf(b1.w);
        __syncthreads();

        bf16x8 af[2], bfr[2];
        #pragma unroll
        for (int mi = 0; mi < 2; mi++) af[mi]  = *(const bf16x8*)&As[wm + mi*16 + l15][quad*8];
        #pragma unroll
        for (int ni = 0; ni < 2; ni++) bfr[ni] = *(const bf16x8*)&Bs[wn + ni*16 + l15][quad*8];
        #pragma unroll
        for (int mi = 0; mi < 2; mi++)
            #pragma unroll
            for (int ni = 0; ni < 2; ni++)
                acc[mi][ni] = __builtin_amdgcn_mfma_f32_16x16x32_bf16(af[mi], bfr[ni], acc[mi][ni], 0, 0, 0);
    }

    #pragma unroll
    for (int mi = 0; mi < 2; mi++) {
        #pragma unroll
        for (int ni = 0; ni < 2; ni++) {
            const int col  = n0 + wn + ni*16 + l15;
            const float bval = bias[col];
            #pragma unroll
            for (int r = 0; r < 4; r++) {
                const int row = m0 + wm + mi*16 + quad*4 + r;
                const float val = acc[mi][ni][r] + bval;
                if (MODE == 0) {
                    const int which = col >> 10;          // 0=q 1=k 2=v
                    const int rem   = col & 1023;
                    const int h = rem >> 6, dd = rem & 63;
                    const int bb = row >> 12, ns = row & 4095;
                    const size_t off = ((size_t)((bb * NH + h) * NSEQ + ns)) * HD + dd;
                    unsigned short* dst = (which == 0) ? out0 : (which == 1) ? out1 : out2;
                    dst[off] = f2bf(val);
                } else {
                    outf[(size_t)row * 1024 + col] = val;   // fp32 output
                }
            }
        }
    }
}

// ---------------------------------------------------------------------------
// Flash attention (MFMA): one block per (b, h, 64-row Q tile). 4 waves x
// 16 Q-rows. Output FP32 [B, N, 1024] (d_out staging).
// ---------------------------------------------------------------------------
__global__ __launch_bounds__(256)
void attn_kernel(const unsigned short* __restrict__ qb,
                 const unsigned short* __restrict__ kb,
                 const unsigned short* __restrict__ vb,
                 float* __restrict__ ob)
{
    __shared__ __align__(16) unsigned short Ks[64][64];      // [key][dd]
    __shared__ __align__(16) unsigned short Vs[64][64];      // [dd][key] (transposed)
    __shared__ __align__(16) unsigned short Ps[4][16][64];   // per-wave P tile

    const int t    = threadIdx.x;
    const int wv   = t >> 6, lane = t & 63, l15 = lane & 15, quad = lane >> 4;
    const int q0   = blockIdx.x * 64;
    const int h    = blockIdx.y, b = blockIdx.z;
    const size_t bh_off = (size_t)(b * NH + h) * NSEQ * HD;
    const unsigned short* Qp = qb + bh_off;
    const unsigned short* Kp = kb + bh_off;
    const unsigned short* Vp = vb + bh_off;

    bf16x8 aq[2];
    {
        const unsigned short* qrow = Qp + (size_t)(q0 + wv*16 + l15) * HD + quad*8;
        aq[0] = *(const bf16x8*)(qrow);
        aq[1] = *(const bf16x8*)(qrow + 32);
    }

    float m_run[4], l_run[4];
    f32x4 acc_o[4] = {};
    #pragma unroll
    for (int r = 0; r < 4; r++) { m_run[r] = -1e30f; l_run[r] = 0.f; }

    const int sr = t >> 2, sc = (t & 3) * 16;   // staging: 64 rows x 64 cols

    for (int kt = 0; kt < NSEQ; kt += 64) {
        short8 kv0 = *(const short8*)(Kp + (size_t)(kt + sr) * HD + sc);
        short8 kv1 = *(const short8*)(Kp + (size_t)(kt + sr) * HD + sc + 8);
        short8 vv0 = *(const short8*)(Vp + (size_t)(kt + sr) * HD + sc);
        short8 vv1 = *(const short8*)(Vp + (size_t)(kt + sr) * HD + sc + 8);
        __syncthreads();                        // prior iter's Ks/Vs reads done
        *(short8*)&Ks[sr][sc]     = kv0;
        *(short8*)&Ks[sr][sc + 8] = kv1;
        #pragma unroll
        for (int j = 0; j < 8; j++) {
            Vs[sc + j][sr]     = (unsigned short)vv0[j];
            Vs[sc + 8 + j][sr] = (unsigned short)vv1[j];
        }
        __syncthreads();

        // S = Q * K^T  (16 q-rows x 64 keys per wave)
        f32x4 accs[4] = {};
        #pragma unroll
        for (int nj = 0; nj < 4; nj++) {
            bf16x8 bk0 = *(const bf16x8*)&Ks[nj*16 + l15][quad*8];
            bf16x8 bk1 = *(const bf16x8*)&Ks[nj*16 + l15][32 + quad*8];
            accs[nj] = __builtin_amdgcn_mfma_f32_16x16x32_bf16(aq[0], bk0, accs[nj], 0, 0, 0);
            accs[nj] = __builtin_amdgcn_mfma_f32_16x16x32_bf16(aq[1], bk1, accs[nj], 0, 0, 0);
        }

        // online softmax per q-row (row = quad*4 + r, 64 keys across 16-lane group)
        #pragma unroll
        for (int r = 0; r < 4; r++) {
            float s0 = accs[0][r] * 0.125f, s1 = accs[1][r] * 0.125f;
            float s2 = accs[2][r] * 0.125f, s3 = accs[3][r] * 0.125f;
            float mx = fmaxf(fmaxf(s0, s1), fmaxf(s2, s3));
            #pragma unroll
            for (int off = 1; off < 16; off <<= 1) mx = fmaxf(mx, __shfl_xor(mx, off));
            const float mnew  = fmaxf(m_run[r], mx);
            const float alpha = __expf(m_run[r] - mnew);
            const float p0 = __expf(s0 - mnew), p1 = __expf(s1 - mnew);
            const float p2 = __expf(s2 - mnew), p3 = __expf(s3 - mnew);
            Ps[wv][quad*4 + r][ 0 + l15] = f2bf(p0);
            Ps[wv][quad*4 + r][16 + l15] = f2bf(p1);
            Ps[wv][quad*4 + r][32 + l15] = f2bf(p2);
            Ps[wv][quad*4 + r][48 + l15] = f2bf(p3);
            float psum = p0 + p1 + p2 + p3;
            #pragma unroll
            for (int off = 1; off < 16; off <<= 1) psum += __shfl_xor(psum, off);
            m_run[r] = mnew;
            l_run[r] = l_run[r] * alpha + psum;
            #pragma unroll
            for (int nj = 0; nj < 4; nj++) acc_o[nj][r] *= alpha;
        }
        __syncthreads();                        // Ps visible (C-layout -> A-layout)

        // O += P * V
        bf16x8 ap0 = *(const bf16x8*)&Ps[wv][l15][quad*8];
        bf16x8 ap1 = *(const bf16x8*)&Ps[wv][l15][32 + quad*8];
        #pragma unroll
        for (int nj = 0; nj < 4; nj++) {
            bf16x8 bv0 = *(const bf16x8*)&Vs[nj*16 + l15][quad*8];
            bf16x8 bv1 = *(const bf16x8*)&Vs[nj*16 + l15][32 + quad*8];
            acc_o[nj] = __builtin_amdgcn_mfma_f32_16x16x32_bf16(ap0, bv0, acc_o[nj], 0, 0, 0);
            acc_o[nj] = __builtin_amdgcn_mfma_f32_16x16x32_bf16(ap1, bv1, acc_o[nj], 0, 0, 0);
        }
    }

    // epilogue: O / l  ->  fp32 [B, N, 1024]
    #pragma unroll
    for (int r = 0; r < 4; r++) {
        const float inv = 1.0f / l_run[r];
        const int row = q0 + wv*16 + quad*4 + r;
        const size_t base = ((size_t)(b * NSEQ + row)) * DIM + h * HD;
        #pragma unroll
        for (int nj = 0; nj < 4; nj++)
            ob[base + nj*16 + l15] = acc_o[nj][r] * inv;
    }
}

extern "C" void kernel_launch(void* const* d_in, const int* in_sizes, int n_in,
                              void* d_out, int out_size, void* d_ws, size_t ws_size,
                              hipStream_t stream)
{
    // Bind inputs by element count (all five are distinct).
    const float *x = nullptr, *w_qkv = nullptr, *b_qkv = nullptr,
                *w_o = nullptr, *b_o = nullptr;
    for (int i = 0; i < n_in; i++) {
        switch (in_sizes[i]) {
            case 8388608: x     = (const float*)d_in[i]; break; // [2,4096,1024]
            case 3145728: w_qkv = (const float*)d_in[i]; break; // [1024,3072]
            case 3072:    b_qkv = (const float*)d_in[i]; break; // [3072]
            case 1048576: w_o   = (const float*)d_in[i]; break; // [1024,1024]
            case 1024:    b_o   = (const float*)d_in[i]; break; // [1024]
        }
    }
    float* out = (float*)d_out;                   // [2,4096,1024] FP32

    const size_t SEG = (size_t)2 * NSEQ * DIM;    // 8,388,608 elems
    unsigned short* qb = (unsigned short*)d_ws;   // bf16 [B,H,N,64]
    unsigned short* kb = qb + SEG;
    unsigned short* vb = kb + SEG;

    // 1) QKV projection + bias -> bf16 q/k/v (48 MB ws)
    gemm_kernel<3072, 0><<<dim3(128, 48), 256, 0, stream>>>(
        x, w_qkv, b_qkv, qb, kb, vb, nullptr);
    // 2) flash attention -> fp32 [B,N,1024] staged in d_out
    attn_kernel<<<dim3(64, NH, 2), 256, 0, stream>>>(qb, kb, vb, out);
    // 3) move attn output to ws (qkv region is dead), then out-projection
    hipMemcpyAsync(d_ws, d_out, SEG * sizeof(float),
                   hipMemcpyDeviceToDevice, stream);
    gemm_kernel<1024, 1><<<dim3(128, 16), 256, 0, stream>>>(
        (const float*)d_ws, w_o, b_o, nullptr, nullptr, nullptr, out);
}

// Round 7
// 820.879 us; speedup vs baseline: 1.2800x; 1.2800x over previous
//
#include <hip/hip_runtime.h>

typedef __attribute__((ext_vector_type(8))) __bf16 bf16x8;
typedef __attribute__((ext_vector_type(8))) short short8;
typedef __attribute__((ext_vector_type(4))) float f32x4;

__device__ __forceinline__ unsigned short f2bf(float f) {
    union { float f; unsigned int i; } c; c.f = f;
    unsigned int r = c.i + 0x7fffu + ((c.i >> 16) & 1u);  // round-nearest-even
    return (unsigned short)(r >> 16);
}

#define DIM 1024
#define NSEQ 4096
#define NH 16
#define HD 64
#define KPAD 72   // LDS row stride (u16): 16B-aligned rows, stride%4==... breaks bank collapse

// ---------------------------------------------------------------------------
// GEMM: C[8192 x N] = A[8192 x 1024] * B[1024 x N] + bias
// A fp32 (bf16-rounded at LDS staging), B/bias fp32.
// MODE 0: scatter bf16 -> Q [B,H,N,64], K [B,H,N,64], V TRANSPOSED [B,H,64,N].
// MODE 1: fp32 store to outf.
// ---------------------------------------------------------------------------
template<int LDB, int MODE>
__global__ __launch_bounds__(256)
void gemm_kernel(const float* __restrict__ A,
                 const float* __restrict__ B,
                 const float* __restrict__ bias,
                 unsigned short* __restrict__ out0,
                 unsigned short* __restrict__ out1,
                 unsigned short* __restrict__ out2,
                 float* __restrict__ outf)
{
    __shared__ __align__(16) unsigned short As[64][32];
    __shared__ __align__(16) unsigned short Bs[64][32];
    const int t    = threadIdx.x;
    const int m0   = blockIdx.x * 64;
    const int n0   = blockIdx.y * 64;
    const int lane = t & 63;
    const int wv   = t >> 6;
    const int l15  = lane & 15;
    const int quad = lane >> 4;
    const int wm   = (wv >> 1) * 32;
    const int wn   = (wv & 1) * 32;
    const int ar   = t >> 2, ac = (t & 3) * 8;
    const int br   = t >> 3, bc = (t & 7) * 8;

    f32x4 acc[2][2] = {};

    for (int kt = 0; kt < 1024; kt += 32) {
        float4 a0 = *(const float4*)(A + (size_t)(m0 + ar) * 1024 + kt + ac);
        float4 a1 = *(const float4*)(A + (size_t)(m0 + ar) * 1024 + kt + ac + 4);
        float4 b0 = *(const float4*)(B + (size_t)(kt + br) * LDB + n0 + bc);
        float4 b1 = *(const float4*)(B + (size_t)(kt + br) * LDB + n0 + bc + 4);

        __syncthreads();
        As[ar][ac + 0] = f2bf(a0.x); As[ar][ac + 1] = f2bf(a0.y);
        As[ar][ac + 2] = f2bf(a0.z); As[ar][ac + 3] = f2bf(a0.w);
        As[ar][ac + 4] = f2bf(a1.x); As[ar][ac + 5] = f2bf(a1.y);
        As[ar][ac + 6] = f2bf(a1.z); As[ar][ac + 7] = f2bf(a1.w);
        Bs[bc + 0][br] = f2bf(b0.x); Bs[bc + 1][br] = f2bf(b0.y);
        Bs[bc + 2][br] = f2bf(b0.z); Bs[bc + 3][br] = f2bf(b0.w);
        Bs[bc + 4][br] = f2bf(b1.x); Bs[bc + 5][br] = f2bf(b1.y);
        Bs[bc + 6][br] = f2bf(b1.z); Bs[bc + 7][br] = f2bf(b1.w);
        __syncthreads();

        bf16x8 af[2], bfr[2];
        #pragma unroll
        for (int mi = 0; mi < 2; mi++) af[mi]  = *(const bf16x8*)&As[wm + mi*16 + l15][quad*8];
        #pragma unroll
        for (int ni = 0; ni < 2; ni++) bfr[ni] = *(const bf16x8*)&Bs[wn + ni*16 + l15][quad*8];
        #pragma unroll
        for (int mi = 0; mi < 2; mi++)
            #pragma unroll
            for (int ni = 0; ni < 2; ni++)
                acc[mi][ni] = __builtin_amdgcn_mfma_f32_16x16x32_bf16(af[mi], bfr[ni], acc[mi][ni], 0, 0, 0);
    }

    #pragma unroll
    for (int mi = 0; mi < 2; mi++) {
        #pragma unroll
        for (int ni = 0; ni < 2; ni++) {
            const int col  = n0 + wn + ni*16 + l15;
            const float bval = bias[col];
            #pragma unroll
            for (int r = 0; r < 4; r++) {
                const int row = m0 + wm + mi*16 + quad*4 + r;
                const float val = acc[mi][ni][r] + bval;
                if (MODE == 0) {
                    const int which = col >> 10;          // 0=q 1=k 2=v
                    const int rem   = col & 1023;
                    const int h = rem >> 6, dd = rem & 63;
                    const int bb = row >> 12, ns = row & 4095;
                    if (which == 2) {
                        // V pre-transposed: [B, H, dd, N]
                        out2[((size_t)((bb * NH + h) * HD + dd)) * NSEQ + ns] = f2bf(val);
                    } else {
                        const size_t off = ((size_t)((bb * NH + h) * NSEQ + ns)) * HD + dd;
                        ((which == 0) ? out0 : out1)[off] = f2bf(val);
                    }
                } else {
                    outf[(size_t)row * 1024 + col] = val;
                }
            }
        }
    }
}

// ---------------------------------------------------------------------------
// Flash attention (MFMA): block = (b, h, 64-row Q tile), 4 waves x 16 Q-rows.
// K natural [key][dd]; V pre-transposed [dd][key] (no in-kernel transpose).
// All LDS rows padded to KPAD=72 u16 -> conflict-free stores + spread reads.
// ---------------------------------------------------------------------------
__global__ __launch_bounds__(256)
void attn_kernel(const unsigned short* __restrict__ qb,
                 const unsigned short* __restrict__ kb,
                 const unsigned short* __restrict__ vb,
                 float* __restrict__ ob)
{
    __shared__ __align__(16) unsigned short Ks[64][KPAD];      // [key][dd]
    __shared__ __align__(16) unsigned short Vt[64][KPAD];      // [dd][key]
    __shared__ __align__(16) unsigned short Ps[4][16][KPAD];   // per-wave P tile

    const int t    = threadIdx.x;
    const int wv   = t >> 6, lane = t & 63, l15 = lane & 15, quad = lane >> 4;
    const int q0   = blockIdx.x * 64;
    const int h    = blockIdx.y, b = blockIdx.z;
    const size_t bh = (size_t)(b * NH + h) * NSEQ * HD;
    const unsigned short* Qp  = qb + bh;
    const unsigned short* Kp  = kb + bh;
    const unsigned short* Vtp = vb + bh;     // [dd][N] within (b,h)

    bf16x8 aq[2];
    {
        const unsigned short* qrow = Qp + (size_t)(q0 + wv*16 + l15) * HD + quad*8;
        aq[0] = *(const bf16x8*)(qrow);
        aq[1] = *(const bf16x8*)(qrow + 32);
    }

    float m_run[4], l_run[4];
    f32x4 acc_o[4] = {};
    #pragma unroll
    for (int r = 0; r < 4; r++) { m_run[r] = -1e30f; l_run[r] = 0.f; }

    const int sr = t >> 2, sc = (t & 3) * 16;   // 64 rows x 64 cols staging

    for (int kt = 0; kt < NSEQ; kt += 64) {
        short8 kv0 = *(const short8*)(Kp  + (size_t)(kt + sr) * HD + sc);
        short8 kv1 = *(const short8*)(Kp  + (size_t)(kt + sr) * HD + sc + 8);
        short8 vv0 = *(const short8*)(Vtp + (size_t)sr * NSEQ + kt + sc);
        short8 vv1 = *(const short8*)(Vtp + (size_t)sr * NSEQ + kt + sc + 8);
        __syncthreads();                        // prior iter's LDS reads done
        *(short8*)&Ks[sr][sc]     = kv0;
        *(short8*)&Ks[sr][sc + 8] = kv1;
        *(short8*)&Vt[sr][sc]     = vv0;        // natural store — no transpose
        *(short8*)&Vt[sr][sc + 8] = vv1;
        __syncthreads();

        // S = Q * K^T  (16 q-rows x 64 keys per wave)
        f32x4 accs[4] = {};
        #pragma unroll
        for (int nj = 0; nj < 4; nj++) {
            bf16x8 bk0 = *(const bf16x8*)&Ks[nj*16 + l15][quad*8];
            bf16x8 bk1 = *(const bf16x8*)&Ks[nj*16 + l15][32 + quad*8];
            accs[nj] = __builtin_amdgcn_mfma_f32_16x16x32_bf16(aq[0], bk0, accs[nj], 0, 0, 0);
            accs[nj] = __builtin_amdgcn_mfma_f32_16x16x32_bf16(aq[1], bk1, accs[nj], 0, 0, 0);
        }

        // online softmax per q-row
        #pragma unroll
        for (int r = 0; r < 4; r++) {
            float s0 = accs[0][r] * 0.125f, s1 = accs[1][r] * 0.125f;
            float s2 = accs[2][r] * 0.125f, s3 = accs[3][r] * 0.125f;
            float mx = fmaxf(fmaxf(s0, s1), fmaxf(s2, s3));
            #pragma unroll
            for (int off = 1; off < 16; off <<= 1) mx = fmaxf(mx, __shfl_xor(mx, off));
            const float mnew  = fmaxf(m_run[r], mx);
            const float alpha = __expf(m_run[r] - mnew);
            const float p0 = __expf(s0 - mnew), p1 = __expf(s1 - mnew);
            const float p2 = __expf(s2 - mnew), p3 = __expf(s3 - mnew);
            Ps[wv][quad*4 + r][ 0 + l15] = f2bf(p0);
            Ps[wv][quad*4 + r][16 + l15] = f2bf(p1);
            Ps[wv][quad*4 + r][32 + l15] = f2bf(p2);
            Ps[wv][quad*4 + r][48 + l15] = f2bf(p3);
            float psum = p0 + p1 + p2 + p3;
            #pragma unroll
            for (int off = 1; off < 16; off <<= 1) psum += __shfl_xor(psum, off);
            m_run[r] = mnew;
            l_run[r] = l_run[r] * alpha + psum;
            #pragma unroll
            for (int nj = 0; nj < 4; nj++) acc_o[nj][r] *= alpha;
        }
        // Ps is wave-private: within-wave ds write->read ordering via lgkmcnt,
        // no barrier needed.

        // O += P * V   (B-fragment from pre-transposed Vt: contiguous b128)
        bf16x8 ap0 = *(const bf16x8*)&Ps[wv][l15][quad*8];
        bf16x8 ap1 = *(const bf16x8*)&Ps[wv][l15][32 + quad*8];
        #pragma unroll
        for (int nj = 0; nj < 4; nj++) {
            bf16x8 bv0 = *(const bf16x8*)&Vt[nj*16 + l15][quad*8];
            bf16x8 bv1 = *(const bf16x8*)&Vt[nj*16 + l15][32 + quad*8];
            acc_o[nj] = __builtin_amdgcn_mfma_f32_16x16x32_bf16(ap0, bv0, acc_o[nj], 0, 0, 0);
            acc_o[nj] = __builtin_amdgcn_mfma_f32_16x16x32_bf16(ap1, bv1, acc_o[nj], 0, 0, 0);
        }
    }

    // epilogue: O / l -> fp32 [B, N, 1024]
    #pragma unroll
    for (int r = 0; r < 4; r++) {
        const float inv = 1.0f / l_run[r];
        const int row = q0 + wv*16 + quad*4 + r;
        const size_t base = ((size_t)(b * NSEQ + row)) * DIM + h * HD;
        #pragma unroll
        for (int nj = 0; nj < 4; nj++)
            ob[base + nj*16 + l15] = acc_o[nj][r] * inv;
    }
}

extern "C" void kernel_launch(void* const* d_in, const int* in_sizes, int n_in,
                              void* d_out, int out_size, void* d_ws, size_t ws_size,
                              hipStream_t stream)
{
    const float *x = nullptr, *w_qkv = nullptr, *b_qkv = nullptr,
                *w_o = nullptr, *b_o = nullptr;
    for (int i = 0; i < n_in; i++) {
        switch (in_sizes[i]) {
            case 8388608: x     = (const float*)d_in[i]; break;
            case 3145728: w_qkv = (const float*)d_in[i]; break;
            case 3072:    b_qkv = (const float*)d_in[i]; break;
            case 1048576: w_o   = (const float*)d_in[i]; break;
            case 1024:    b_o   = (const float*)d_in[i]; break;
        }
    }
    float* out = (float*)d_out;                   // [2,4096,1024] fp32

    const size_t SEG = (size_t)2 * NSEQ * DIM;    // 8,388,608 elems
    unsigned short* qb = (unsigned short*)d_ws;   // bf16 [B,H,N,64]
    unsigned short* kb = qb + SEG;                // bf16 [B,H,N,64]
    unsigned short* vb = kb + SEG;                // bf16 [B,H,64,N] (transposed)

    gemm_kernel<3072, 0><<<dim3(128, 48), 256, 0, stream>>>(
        x, w_qkv, b_qkv, qb, kb, vb, nullptr);

    const size_t qkv_bytes = 3 * SEG * sizeof(unsigned short);   // 50.3 MB
    if (ws_size >= qkv_bytes + SEG * sizeof(float)) {
        // attention output fp32 directly in ws after qkv — no memcpy
        float* ao = (float*)((char*)d_ws + qkv_bytes);
        attn_kernel<<<dim3(64, NH, 2), 256, 0, stream>>>(qb, kb, vb, ao);
        gemm_kernel<1024, 1><<<dim3(128, 16), 256, 0, stream>>>(
            ao, w_o, b_o, nullptr, nullptr, nullptr, out);
    } else {
        attn_kernel<<<dim3(64, NH, 2), 256, 0, stream>>>(qb, kb, vb, out);
        hipMemcpyAsync(d_ws, d_out, SEG * sizeof(float),
                       hipMemcpyDeviceToDevice, stream);
        gemm_kernel<1024, 1><<<dim3(128, 16), 256, 0, stream>>>(
            (const float*)d_ws, w_o, b_o, nullptr, nullptr, nullptr, out);
    }
}

// Round 8
// 617.341 us; speedup vs baseline: 1.7020x; 1.3297x over previous
//
#include <hip/hip_runtime.h>

typedef __attribute__((ext_vector_type(8))) __bf16 bf16x8;
typedef __attribute__((ext_vector_type(8))) short short8;
typedef __attribute__((ext_vector_type(4))) float f32x4;

__device__ __forceinline__ unsigned short f2bf(float f) {
    union { float f; unsigned int i; } c; c.f = f;
    unsigned int r = c.i + 0x7fffu + ((c.i >> 16) & 1u);  // round-nearest-even
    return (unsigned short)(r >> 16);
}

#define DIM 1024
#define NSEQ 4096
#define NH 16
#define HD 64
#define KPAD 72   // LDS row stride (u16): 16B-aligned, breaks bank collapse

// ---------------------------------------------------------------------------
// GEMM (unchanged from R7): C[8192 x N] = A * B + bias
// MODE 0: scatter bf16 -> Q [B,H,N,64], K [B,H,N,64], V transposed [B,H,64,N].
// MODE 1: fp32 store to outf.
// ---------------------------------------------------------------------------
template<int LDB, int MODE>
__global__ __launch_bounds__(256)
void gemm_kernel(const float* __restrict__ A,
                 const float* __restrict__ B,
                 const float* __restrict__ bias,
                 unsigned short* __restrict__ out0,
                 unsigned short* __restrict__ out1,
                 unsigned short* __restrict__ out2,
                 float* __restrict__ outf)
{
    __shared__ __align__(16) unsigned short As[64][32];
    __shared__ __align__(16) unsigned short Bs[64][32];
    const int t    = threadIdx.x;
    const int m0   = blockIdx.x * 64;
    const int n0   = blockIdx.y * 64;
    const int lane = t & 63;
    const int wv   = t >> 6;
    const int l15  = lane & 15;
    const int quad = lane >> 4;
    const int wm   = (wv >> 1) * 32;
    const int wn   = (wv & 1) * 32;
    const int ar   = t >> 2, ac = (t & 3) * 8;
    const int br   = t >> 3, bc = (t & 7) * 8;

    f32x4 acc[2][2] = {};

    for (int kt = 0; kt < 1024; kt += 32) {
        float4 a0 = *(const float4*)(A + (size_t)(m0 + ar) * 1024 + kt + ac);
        float4 a1 = *(const float4*)(A + (size_t)(m0 + ar) * 1024 + kt + ac + 4);
        float4 b0 = *(const float4*)(B + (size_t)(kt + br) * LDB + n0 + bc);
        float4 b1 = *(const float4*)(B + (size_t)(kt + br) * LDB + n0 + bc + 4);

        __syncthreads();
        As[ar][ac + 0] = f2bf(a0.x); As[ar][ac + 1] = f2bf(a0.y);
        As[ar][ac + 2] = f2bf(a0.z); As[ar][ac + 3] = f2bf(a0.w);
        As[ar][ac + 4] = f2bf(a1.x); As[ar][ac + 5] = f2bf(a1.y);
        As[ar][ac + 6] = f2bf(a1.z); As[ar][ac + 7] = f2bf(a1.w);
        Bs[bc + 0][br] = f2bf(b0.x); Bs[bc + 1][br] = f2bf(b0.y);
        Bs[bc + 2][br] = f2bf(b0.z); Bs[bc + 3][br] = f2bf(b0.w);
        Bs[bc + 4][br] = f2bf(b1.x); Bs[bc + 5][br] = f2bf(b1.y);
        Bs[bc + 6][br] = f2bf(b1.z); Bs[bc + 7][br] = f2bf(b1.w);
        __syncthreads();

        bf16x8 af[2], bfr[2];
        #pragma unroll
        for (int mi = 0; mi < 2; mi++) af[mi]  = *(const bf16x8*)&As[wm + mi*16 + l15][quad*8];
        #pragma unroll
        for (int ni = 0; ni < 2; ni++) bfr[ni] = *(const bf16x8*)&Bs[wn + ni*16 + l15][quad*8];
        #pragma unroll
        for (int mi = 0; mi < 2; mi++)
            #pragma unroll
            for (int ni = 0; ni < 2; ni++)
                acc[mi][ni] = __builtin_amdgcn_mfma_f32_16x16x32_bf16(af[mi], bfr[ni], acc[mi][ni], 0, 0, 0);
    }

    #pragma unroll
    for (int mi = 0; mi < 2; mi++) {
        #pragma unroll
        for (int ni = 0; ni < 2; ni++) {
            const int col  = n0 + wn + ni*16 + l15;
            const float bval = bias[col];
            #pragma unroll
            for (int r = 0; r < 4; r++) {
                const int row = m0 + wm + mi*16 + quad*4 + r;
                const float val = acc[mi][ni][r] + bval;
                if (MODE == 0) {
                    const int which = col >> 10;
                    const int rem   = col & 1023;
                    const int h = rem >> 6, dd = rem & 63;
                    const int bb = row >> 12, ns = row & 4095;
                    if (which == 2) {
                        out2[((size_t)((bb * NH + h) * HD + dd)) * NSEQ + ns] = f2bf(val);
                    } else {
                        const size_t off = ((size_t)((bb * NH + h) * NSEQ + ns)) * HD + dd;
                        ((which == 0) ? out0 : out1)[off] = f2bf(val);
                    }
                } else {
                    outf[(size_t)row * 1024 + col] = val;
                }
            }
        }
    }
}

// ---------------------------------------------------------------------------
// Flash attention v3: block = (b, h, 128-row Q tile), 4 waves x 32 Q-rows.
// Fixed-max softmax (M=8, exp2 domain): no running max, no rescale, no
// per-tile shuffle reductions. P truncated to bf16; l sums truncated p so
// normalization cancels the bias. K natural, V pre-transposed.
// ---------------------------------------------------------------------------
#define C_LOG2E 0.1803368801111183f    // 0.125 * log2(e)
#define M_LOG2  11.541560327111707f    // 8 * log2(e)

__global__ __launch_bounds__(256, 4)
void attn_kernel(const unsigned short* __restrict__ qb,
                 const unsigned short* __restrict__ kb,
                 const unsigned short* __restrict__ vb,
                 float* __restrict__ ob)
{
    __shared__ __align__(16) unsigned short Ks[64][KPAD];     // [key][dd]
    __shared__ __align__(16) unsigned short Vt[64][KPAD];     // [dd][key]
    __shared__ __align__(16) unsigned short Ps[4][32][KPAD];  // per-wave P tile

    const int t    = threadIdx.x;
    const int wv   = t >> 6, lane = t & 63, l15 = lane & 15, quad = lane >> 4;
    const int q0   = blockIdx.x * 128;
    const int h    = blockIdx.y, b = blockIdx.z;
    const size_t bh = (size_t)(b * NH + h) * NSEQ * HD;
    const unsigned short* Qp  = qb + bh;
    const unsigned short* Kp  = kb + bh;
    const unsigned short* Vtp = vb + bh;     // [dd][N]

    // 32 q-rows per wave: sub-tiles mi=0,1 of 16 rows
    bf16x8 aq[2][2];
    #pragma unroll
    for (int mi = 0; mi < 2; mi++) {
        const unsigned short* qrow =
            Qp + (size_t)(q0 + wv*32 + mi*16 + l15) * HD + quad*8;
        aq[mi][0] = *(const bf16x8*)(qrow);
        aq[mi][1] = *(const bf16x8*)(qrow + 32);
    }

    float l_loc[2][4] = {};
    f32x4 acc_o[2][4] = {};

    const int sr = t >> 2, sc = (t & 3) * 16;   // 64x64 staging

    for (int kt = 0; kt < NSEQ; kt += 64) {
        short8 kv0 = *(const short8*)(Kp  + (size_t)(kt + sr) * HD + sc);
        short8 kv1 = *(const short8*)(Kp  + (size_t)(kt + sr) * HD + sc + 8);
        short8 vv0 = *(const short8*)(Vtp + (size_t)sr * NSEQ + kt + sc);
        short8 vv1 = *(const short8*)(Vtp + (size_t)sr * NSEQ + kt + sc + 8);
        __syncthreads();
        *(short8*)&Ks[sr][sc]     = kv0;
        *(short8*)&Ks[sr][sc + 8] = kv1;
        *(short8*)&Vt[sr][sc]     = vv0;
        *(short8*)&Vt[sr][sc + 8] = vv1;
        __syncthreads();

        // S = Q K^T : 32 q-rows x 64 keys per wave
        f32x4 accs[2][4] = {};
        #pragma unroll
        for (int nj = 0; nj < 4; nj++) {
            bf16x8 bk0 = *(const bf16x8*)&Ks[nj*16 + l15][quad*8];
            bf16x8 bk1 = *(const bf16x8*)&Ks[nj*16 + l15][32 + quad*8];
            #pragma unroll
            for (int mi = 0; mi < 2; mi++) {
                accs[mi][nj] = __builtin_amdgcn_mfma_f32_16x16x32_bf16(aq[mi][0], bk0, accs[mi][nj], 0, 0, 0);
                accs[mi][nj] = __builtin_amdgcn_mfma_f32_16x16x32_bf16(aq[mi][1], bk1, accs[mi][nj], 0, 0, 0);
            }
        }

        // fixed-max softmax: p = 2^(s*c - M); store trunc-bf16; l += trunc(p)
        #pragma unroll
        for (int mi = 0; mi < 2; mi++) {
            #pragma unroll
            for (int r = 0; r < 4; r++) {
                const int prow = mi*16 + quad*4 + r;
                float lsum = 0.f;
                #pragma unroll
                for (int nj = 0; nj < 4; nj++) {
                    const float p = exp2f(fmaf(accs[mi][nj][r], C_LOG2E, -M_LOG2));
                    const unsigned int pb = __float_as_uint(p);
                    Ps[wv][prow][nj*16 + l15] = (unsigned short)(pb >> 16);
                    lsum += __uint_as_float(pb & 0xffff0000u);
                }
                l_loc[mi][r] += lsum;
            }
        }
        // Ps wave-private: ds ordering within wave via lgkmcnt, no barrier.

        // O += P V
        #pragma unroll
        for (int nj = 0; nj < 4; nj++) {
            bf16x8 bv0 = *(const bf16x8*)&Vt[nj*16 + l15][quad*8];
            bf16x8 bv1 = *(const bf16x8*)&Vt[nj*16 + l15][32 + quad*8];
            #pragma unroll
            for (int mi = 0; mi < 2; mi++) {
                bf16x8 ap0 = *(const bf16x8*)&Ps[wv][mi*16 + l15][quad*8];
                bf16x8 ap1 = *(const bf16x8*)&Ps[wv][mi*16 + l15][32 + quad*8];
                acc_o[mi][nj] = __builtin_amdgcn_mfma_f32_16x16x32_bf16(ap0, bv0, acc_o[mi][nj], 0, 0, 0);
                acc_o[mi][nj] = __builtin_amdgcn_mfma_f32_16x16x32_bf16(ap1, bv1, acc_o[mi][nj], 0, 0, 0);
            }
        }
    }

    // epilogue: reduce l across the 16-lane group, O/l -> fp32 [B,N,1024]
    #pragma unroll
    for (int mi = 0; mi < 2; mi++) {
        #pragma unroll
        for (int r = 0; r < 4; r++) {
            float l = l_loc[mi][r];
            #pragma unroll
            for (int off = 1; off < 16; off <<= 1) l += __shfl_xor(l, off);
            const float inv = 1.0f / l;
            const int row = q0 + wv*32 + mi*16 + quad*4 + r;
            const size_t base = ((size_t)(b * NSEQ + row)) * DIM + h * HD;
            #pragma unroll
            for (int nj = 0; nj < 4; nj++)
                ob[base + nj*16 + l15] = acc_o[mi][nj][r] * inv;
        }
    }
}

extern "C" void kernel_launch(void* const* d_in, const int* in_sizes, int n_in,
                              void* d_out, int out_size, void* d_ws, size_t ws_size,
                              hipStream_t stream)
{
    const float *x = nullptr, *w_qkv = nullptr, *b_qkv = nullptr,
                *w_o = nullptr, *b_o = nullptr;
    for (int i = 0; i < n_in; i++) {
        switch (in_sizes[i]) {
            case 8388608: x     = (const float*)d_in[i]; break;
            case 3145728: w_qkv = (const float*)d_in[i]; break;
            case 3072:    b_qkv = (const float*)d_in[i]; break;
            case 1048576: w_o   = (const float*)d_in[i]; break;
            case 1024:    b_o   = (const float*)d_in[i]; break;
        }
    }
    float* out = (float*)d_out;                   // [2,4096,1024] fp32

    const size_t SEG = (size_t)2 * NSEQ * DIM;    // 8,388,608 elems
    unsigned short* qb = (unsigned short*)d_ws;   // bf16 [B,H,N,64]
    unsigned short* kb = qb + SEG;                // bf16 [B,H,N,64]
    unsigned short* vb = kb + SEG;                // bf16 [B,H,64,N]

    gemm_kernel<3072, 0><<<dim3(128, 48), 256, 0, stream>>>(
        x, w_qkv, b_qkv, qb, kb, vb, nullptr);

    const size_t qkv_bytes = 3 * SEG * sizeof(unsigned short);   // 50.3 MB
    if (ws_size >= qkv_bytes + SEG * sizeof(float)) {
        float* ao = (float*)((char*)d_ws + qkv_bytes);
        attn_kernel<<<dim3(32, NH, 2), 256, 0, stream>>>(qb, kb, vb, ao);
        gemm_kernel<1024, 1><<<dim3(128, 16), 256, 0, stream>>>(
            ao, w_o, b_o, nullptr, nullptr, nullptr, out);
    } else {
        attn_kernel<<<dim3(32, NH, 2), 256, 0, stream>>>(qb, kb, vb, out);
        hipMemcpyAsync(d_ws, d_out, SEG * sizeof(float),
                       hipMemcpyDeviceToDevice, stream);
        gemm_kernel<1024, 1><<<dim3(128, 16), 256, 0, stream>>>(
            (const float*)d_ws, w_o, b_o, nullptr, nullptr, nullptr, out);
    }
}

// Round 9
// 421.059 us; speedup vs baseline: 2.4954x; 1.4662x over previous
//
#include <hip/hip_runtime.h>

typedef __attribute__((ext_vector_type(8))) __bf16 bf16x8;
typedef __attribute__((ext_vector_type(8))) short short8;
typedef __attribute__((ext_vector_type(4))) float f32x4;

__device__ __forceinline__ unsigned short f2bf(float f) {
    union { float f; unsigned int i; } c; c.f = f;
    unsigned int r = c.i + 0x7fffu + ((c.i >> 16) & 1u);  // round-nearest-even
    return (unsigned short)(r >> 16);
}

// async global->LDS, 16B per lane; LDS dest must be base + lane*16 in wave order
__device__ __forceinline__ void async_cp16(const unsigned short* g, unsigned short* l) {
    __builtin_amdgcn_global_load_lds(
        (const __attribute__((address_space(1))) unsigned int*)g,
        (__attribute__((address_space(3))) unsigned int*)l, 16, 0, 0);
}

#define DIM 1024
#define NSEQ 4096
#define NH 16
#define HD 64
#define KPAD 72   // attn LDS row stride (u16)

// ---------------------------------------------------------------------------
// fp32 -> bf16 copy-convert, 8 elems/thread
// ---------------------------------------------------------------------------
__global__ __launch_bounds__(256)
void conv_kernel(const float* __restrict__ in, unsigned short* __restrict__ out)
{
    const int i = blockIdx.x * 256 + threadIdx.x;
    const float4 a0 = ((const float4*)in)[i * 2];
    const float4 a1 = ((const float4*)in)[i * 2 + 1];
    short8 v;
    v[0] = (short)f2bf(a0.x); v[1] = (short)f2bf(a0.y);
    v[2] = (short)f2bf(a0.z); v[3] = (short)f2bf(a0.w);
    v[4] = (short)f2bf(a1.x); v[5] = (short)f2bf(a1.y);
    v[6] = (short)f2bf(a1.z); v[7] = (short)f2bf(a1.w);
    ((short8*)out)[i] = v;
}

// ---------------------------------------------------------------------------
// w [K][N] fp32 -> wT [N][K] bf16, 64x64 LDS tile transpose
// ---------------------------------------------------------------------------
template<int N, int K>
__global__ __launch_bounds__(256)
void transpose_conv_kernel(const float* __restrict__ in, unsigned short* __restrict__ out)
{
    __shared__ unsigned short Ls[64][65];
    const int t  = threadIdx.x;
    const int k0 = blockIdx.x * 64, n0 = blockIdx.y * 64;
    const int kl = t >> 2, nl = (t & 3) * 16;
    const float* src = in + (size_t)(k0 + kl) * N + n0 + nl;
    #pragma unroll
    for (int i = 0; i < 4; i++) {
        float4 a = *(const float4*)(src + i * 4);
        Ls[kl][nl + i*4 + 0] = f2bf(a.x); Ls[kl][nl + i*4 + 1] = f2bf(a.y);
        Ls[kl][nl + i*4 + 2] = f2bf(a.z); Ls[kl][nl + i*4 + 3] = f2bf(a.w);
    }
    __syncthreads();
    const int kl2 = (t & 7) * 8;
    #pragma unroll
    for (int i = 0; i < 2; i++) {
        const int nl2 = (t >> 3) + i * 32;
        short8 v;
        #pragma unroll
        for (int j = 0; j < 8; j++) v[j] = (short)Ls[kl2 + j][nl2];
        *(short8*)(out + (size_t)(n0 + nl2) * K + k0 + kl2) = v;
    }
}

// ---------------------------------------------------------------------------
// m97-style GEMM: C[M x N] = A[M][1024]bf16 * Bt[N][1024]bf16^T + bias(fp32)
// 128x128 tile, BK=32, 4 waves x 64x64 quadrant, global_load_lds staging.
// MODE 0 (N=3072): scatter bf16 -> Q[Z,H,N,64], K[Z,H,N,64], V^T[Z,H,64,N]
// MODE 1 (N=1024): fp32 store to outf.
// ---------------------------------------------------------------------------
template<int MODE>
__global__ __launch_bounds__(256)
void gemm_kernel(const unsigned short* __restrict__ A,
                 const unsigned short* __restrict__ Bt,
                 const float* __restrict__ bias,
                 unsigned short* __restrict__ out0,
                 unsigned short* __restrict__ out1,
                 unsigned short* __restrict__ out2,
                 float* __restrict__ outf)
{
    __shared__ __align__(16) unsigned short As[128][32];
    __shared__ __align__(16) unsigned short Bs[128][32];
    const int t    = threadIdx.x;
    const int m0   = blockIdx.x * 128, n0 = blockIdx.y * 128;
    const int lane = t & 63, wv = t >> 6;
    const int l15  = lane & 15, quad = lane >> 4;
    const int wm   = (wv >> 1) * 64, wn = (wv & 1) * 64;
    const int sr   = wv * 16 + (lane >> 2);     // staging row (0..63)
    const int sc   = (lane & 3) * 8;            // staging col (k)
    const unsigned short* Ag = A  + (size_t)m0 * 1024;
    const unsigned short* Bg = Bt + (size_t)n0 * 1024;

    f32x4 acc[4][4] = {};

    for (int kt = 0; kt < 1024; kt += 32) {
        __syncthreads();                        // prior iter's LDS reads done
        async_cp16(Ag + (size_t)(sr)      * 1024 + kt + sc, &As[sr][sc]);
        async_cp16(Ag + (size_t)(sr + 64) * 1024 + kt + sc, &As[sr + 64][sc]);
        async_cp16(Bg + (size_t)(sr)      * 1024 + kt + sc, &Bs[sr][sc]);
        async_cp16(Bg + (size_t)(sr + 64) * 1024 + kt + sc, &Bs[sr + 64][sc]);
        __syncthreads();                        // drains vmcnt (loads landed)

        bf16x8 af[4], bfr[4];
        #pragma unroll
        for (int mi = 0; mi < 4; mi++) af[mi]  = *(const bf16x8*)&As[wm + mi*16 + l15][quad*8];
        #pragma unroll
        for (int ni = 0; ni < 4; ni++) bfr[ni] = *(const bf16x8*)&Bs[wn + ni*16 + l15][quad*8];
        #pragma unroll
        for (int mi = 0; mi < 4; mi++)
            #pragma unroll
            for (int ni = 0; ni < 4; ni++)
                acc[mi][ni] = __builtin_amdgcn_mfma_f32_16x16x32_bf16(af[mi], bfr[ni], acc[mi][ni], 0, 0, 0);
    }

    #pragma unroll
    for (int mi = 0; mi < 4; mi++) {
        #pragma unroll
        for (int ni = 0; ni < 4; ni++) {
            const int col  = n0 + wn + ni*16 + l15;
            const float bval = bias[col];
            #pragma unroll
            for (int r = 0; r < 4; r++) {
                const int row = m0 + wm + mi*16 + quad*4 + r;
                const float val = acc[mi][ni][r] + bval;
                if (MODE == 0) {
                    const int which = col >> 10;          // 0=q 1=k 2=v
                    const int rem   = col & 1023;
                    const int h = rem >> 6, dd = rem & 63;
                    const int bb = row >> 12, ns = row & 4095;
                    if (which == 2) {
                        out2[((size_t)((bb * NH + h) * HD + dd)) * NSEQ + ns] = f2bf(val);
                    } else {
                        const size_t off = ((size_t)((bb * NH + h) * NSEQ + ns)) * HD + dd;
                        ((which == 0) ? out0 : out1)[off] = f2bf(val);
                    }
                } else {
                    outf[(size_t)row * 1024 + col] = val;
                }
            }
        }
    }
}

// ---------------------------------------------------------------------------
// Flash attention (R8 structure): block=(z,h,128 q-rows), 4 waves x 32 rows.
// Fixed-max softmax (M=8, exp2 domain), trunc-bf16 P, deferred l-reduction.
// Output now bf16 (feeds GEMM2 directly).
// ---------------------------------------------------------------------------
#define C_LOG2E 0.1803368801111183f    // 0.125 * log2(e)
#define M_LOG2  11.541560327111707f    // 8 * log2(e)

__global__ __launch_bounds__(256, 4)
void attn_kernel(const unsigned short* __restrict__ qb,
                 const unsigned short* __restrict__ kb,
                 const unsigned short* __restrict__ vb,
                 unsigned short* __restrict__ ob)
{
    __shared__ __align__(16) unsigned short Ks[64][KPAD];
    __shared__ __align__(16) unsigned short Vt[64][KPAD];
    __shared__ __align__(16) unsigned short Ps[4][32][KPAD];

    const int t    = threadIdx.x;
    const int wv   = t >> 6, lane = t & 63, l15 = lane & 15, quad = lane >> 4;
    const int q0   = blockIdx.x * 128;
    const int h    = blockIdx.y, b = blockIdx.z;
    const size_t bh = (size_t)(b * NH + h) * NSEQ * HD;
    const unsigned short* Qp  = qb + bh;
    const unsigned short* Kp  = kb + bh;
    const unsigned short* Vtp = vb + bh;

    bf16x8 aq[2][2];
    #pragma unroll
    for (int mi = 0; mi < 2; mi++) {
        const unsigned short* qrow =
            Qp + (size_t)(q0 + wv*32 + mi*16 + l15) * HD + quad*8;
        aq[mi][0] = *(const bf16x8*)(qrow);
        aq[mi][1] = *(const bf16x8*)(qrow + 32);
    }

    float l_loc[2][4] = {};
    f32x4 acc_o[2][4] = {};

    const int sr = t >> 2, sc = (t & 3) * 16;

    for (int kt = 0; kt < NSEQ; kt += 64) {
        short8 kv0 = *(const short8*)(Kp  + (size_t)(kt + sr) * HD + sc);
        short8 kv1 = *(const short8*)(Kp  + (size_t)(kt + sr) * HD + sc + 8);
        short8 vv0 = *(const short8*)(Vtp + (size_t)sr * NSEQ + kt + sc);
        short8 vv1 = *(const short8*)(Vtp + (size_t)sr * NSEQ + kt + sc + 8);
        __syncthreads();
        *(short8*)&Ks[sr][sc]     = kv0;
        *(short8*)&Ks[sr][sc + 8] = kv1;
        *(short8*)&Vt[sr][sc]     = vv0;
        *(short8*)&Vt[sr][sc + 8] = vv1;
        __syncthreads();

        f32x4 accs[2][4] = {};
        #pragma unroll
        for (int nj = 0; nj < 4; nj++) {
            bf16x8 bk0 = *(const bf16x8*)&Ks[nj*16 + l15][quad*8];
            bf16x8 bk1 = *(const bf16x8*)&Ks[nj*16 + l15][32 + quad*8];
            #pragma unroll
            for (int mi = 0; mi < 2; mi++) {
                accs[mi][nj] = __builtin_amdgcn_mfma_f32_16x16x32_bf16(aq[mi][0], bk0, accs[mi][nj], 0, 0, 0);
                accs[mi][nj] = __builtin_amdgcn_mfma_f32_16x16x32_bf16(aq[mi][1], bk1, accs[mi][nj], 0, 0, 0);
            }
        }

        #pragma unroll
        for (int mi = 0; mi < 2; mi++) {
            #pragma unroll
            for (int r = 0; r < 4; r++) {
                const int prow = mi*16 + quad*4 + r;
                float lsum = 0.f;
                #pragma unroll
                for (int nj = 0; nj < 4; nj++) {
                    const float p = exp2f(fmaf(accs[mi][nj][r], C_LOG2E, -M_LOG2));
                    const unsigned int pb = __float_as_uint(p);
                    Ps[wv][prow][nj*16 + l15] = (unsigned short)(pb >> 16);
                    lsum += __uint_as_float(pb & 0xffff0000u);
                }
                l_loc[mi][r] += lsum;
            }
        }

        #pragma unroll
        for (int nj = 0; nj < 4; nj++) {
            bf16x8 bv0 = *(const bf16x8*)&Vt[nj*16 + l15][quad*8];
            bf16x8 bv1 = *(const bf16x8*)&Vt[nj*16 + l15][32 + quad*8];
            #pragma unroll
            for (int mi = 0; mi < 2; mi++) {
                bf16x8 ap0 = *(const bf16x8*)&Ps[wv][mi*16 + l15][quad*8];
                bf16x8 ap1 = *(const bf16x8*)&Ps[wv][mi*16 + l15][32 + quad*8];
                acc_o[mi][nj] = __builtin_amdgcn_mfma_f32_16x16x32_bf16(ap0, bv0, acc_o[mi][nj], 0, 0, 0);
                acc_o[mi][nj] = __builtin_amdgcn_mfma_f32_16x16x32_bf16(ap1, bv1, acc_o[mi][nj], 0, 0, 0);
            }
        }
    }

    #pragma unroll
    for (int mi = 0; mi < 2; mi++) {
        #pragma unroll
        for (int r = 0; r < 4; r++) {
            float l = l_loc[mi][r];
            #pragma unroll
            for (int off = 1; off < 16; off <<= 1) l += __shfl_xor(l, off);
            const float inv = 1.0f / l;
            const int row = q0 + wv*32 + mi*16 + quad*4 + r;
            const size_t base = ((size_t)(b * NSEQ + row)) * DIM + h * HD;
            #pragma unroll
            for (int nj = 0; nj < 4; nj++)
                ob[base + nj*16 + l15] = f2bf(acc_o[mi][nj][r] * inv);
        }
    }
}

extern "C" void kernel_launch(void* const* d_in, const int* in_sizes, int n_in,
                              void* d_out, int out_size, void* d_ws, size_t ws_size,
                              hipStream_t stream)
{
    const float *x = nullptr, *w_qkv = nullptr, *b_qkv = nullptr,
                *w_o = nullptr, *b_o = nullptr;
    for (int i = 0; i < n_in; i++) {
        switch (in_sizes[i]) {
            case 8388608: x     = (const float*)d_in[i]; break;
            case 3145728: w_qkv = (const float*)d_in[i]; break;
            case 3072:    b_qkv = (const float*)d_in[i]; break;
            case 1048576: w_o   = (const float*)d_in[i]; break;
            case 1024:    b_o   = (const float*)d_in[i]; break;
        }
    }
    float* out = (float*)d_out;                     // [2,4096,1024] fp32

    const size_t WQB  = (size_t)3072 * 1024;        // elems
    const size_t WOB  = (size_t)1024 * 1024;
    const size_t SEGB = (size_t)NSEQ * DIM;         // 4,194,304 elems / batch

    char* p = (char*)d_ws;
    unsigned short* wqb = (unsigned short*)p;  p += WQB * 2;
    unsigned short* wob = (unsigned short*)p;  p += WOB * 2;

    // weight prep (once)
    transpose_conv_kernel<3072, 1024><<<dim3(16, 48), 256, 0, stream>>>(w_qkv, wqb);
    transpose_conv_kernel<1024, 1024><<<dim3(16, 16), 256, 0, stream>>>(w_o, wob);

    const size_t tier1_bytes = (WQB + WOB + 2*SEGB + 3*2*SEGB) * 2;  // 75.5 MB
    if (ws_size >= tier1_bytes) {
        unsigned short* xb = (unsigned short*)p;  p += 2 * SEGB * 2;
        unsigned short* qb = (unsigned short*)p;  p += 2 * SEGB * 2;
        unsigned short* kb = (unsigned short*)p;  p += 2 * SEGB * 2;
        unsigned short* vb = (unsigned short*)p;
        unsigned short* ao = xb;                  // xb dead after GEMM1
        conv_kernel<<<4096, 256, 0, stream>>>(x, xb);
        gemm_kernel<0><<<dim3(64, 24), 256, 0, stream>>>(xb, wqb, b_qkv, qb, kb, vb, nullptr);
        attn_kernel<<<dim3(32, NH, 2), 256, 0, stream>>>(qb, kb, vb, ao);
        gemm_kernel<1><<<dim3(64, 8), 256, 0, stream>>>(ao, wob, b_o, nullptr, nullptr, nullptr, out);
    } else {
        // per-batch: peak 41.9 MB (< 50.33 MB proven available in R6-R8)
        unsigned short* xb = (unsigned short*)p;  p += SEGB * 2;
        unsigned short* qb = (unsigned short*)p;  p += SEGB * 2;
        unsigned short* kb = (unsigned short*)p;  p += SEGB * 2;
        unsigned short* vb = (unsigned short*)p;
        unsigned short* ao = xb;
        for (int b = 0; b < 2; b++) {
            conv_kernel<<<2048, 256, 0, stream>>>(x + b * SEGB, xb);
            gemm_kernel<0><<<dim3(32, 24), 256, 0, stream>>>(xb, wqb, b_qkv, qb, kb, vb, nullptr);
            attn_kernel<<<dim3(32, NH, 1), 256, 0, stream>>>(qb, kb, vb, ao);
            gemm_kernel<1><<<dim3(32, 8), 256, 0, stream>>>(ao, wob, b_o, nullptr, nullptr, nullptr, out + b * SEGB);
        }
    }
}

// Round 10
// 392.731 us; speedup vs baseline: 2.6754x; 1.0721x over previous
//
#include <hip/hip_runtime.h>

typedef __attribute__((ext_vector_type(8))) __bf16 bf16x8;
typedef __attribute__((ext_vector_type(8))) short short8;
typedef __attribute__((ext_vector_type(4))) float f32x4;

__device__ __forceinline__ unsigned short f2bf(float f) {
    union { float f; unsigned int i; } c; c.f = f;
    unsigned int r = c.i + 0x7fffu + ((c.i >> 16) & 1u);  // round-nearest-even
    return (unsigned short)(r >> 16);
}

#if __has_builtin(__builtin_amdgcn_exp2f)
#define FAST_EXP2(x) __builtin_amdgcn_exp2f(x)     // single v_exp_f32
#else
#define FAST_EXP2(x) __expf((x) * 0.6931471805599453f)
#endif

// async global->LDS, 16B per lane; LDS dest must be base + lane*16 in wave order
__device__ __forceinline__ void async_cp16(const unsigned short* g, unsigned short* l) {
    __builtin_amdgcn_global_load_lds(
        (const __attribute__((address_space(1))) unsigned int*)g,
        (__attribute__((address_space(3))) unsigned int*)l, 16, 0, 0);
}

#define DIM 1024
#define NSEQ 4096
#define NH 16
#define HD 64
#define KPAD 72   // attn LDS row stride (u16)

// ---------------------------------------------------------------------------
// fp32 -> bf16 copy-convert, 8 elems/thread
// ---------------------------------------------------------------------------
__global__ __launch_bounds__(256)
void conv_kernel(const float* __restrict__ in, unsigned short* __restrict__ out)
{
    const int i = blockIdx.x * 256 + threadIdx.x;
    const float4 a0 = ((const float4*)in)[i * 2];
    const float4 a1 = ((const float4*)in)[i * 2 + 1];
    short8 v;
    v[0] = (short)f2bf(a0.x); v[1] = (short)f2bf(a0.y);
    v[2] = (short)f2bf(a0.z); v[3] = (short)f2bf(a0.w);
    v[4] = (short)f2bf(a1.x); v[5] = (short)f2bf(a1.y);
    v[6] = (short)f2bf(a1.z); v[7] = (short)f2bf(a1.w);
    ((short8*)out)[i] = v;
}

// ---------------------------------------------------------------------------
// w [K][N] fp32 -> wT [N][K] bf16, 64x64 LDS tile transpose
// ---------------------------------------------------------------------------
template<int N, int K>
__global__ __launch_bounds__(256)
void transpose_conv_kernel(const float* __restrict__ in, unsigned short* __restrict__ out)
{
    __shared__ unsigned short Ls[64][65];
    const int t  = threadIdx.x;
    const int k0 = blockIdx.x * 64, n0 = blockIdx.y * 64;
    const int kl = t >> 2, nl = (t & 3) * 16;
    const float* src = in + (size_t)(k0 + kl) * N + n0 + nl;
    #pragma unroll
    for (int i = 0; i < 4; i++) {
        float4 a = *(const float4*)(src + i * 4);
        Ls[kl][nl + i*4 + 0] = f2bf(a.x); Ls[kl][nl + i*4 + 1] = f2bf(a.y);
        Ls[kl][nl + i*4 + 2] = f2bf(a.z); Ls[kl][nl + i*4 + 3] = f2bf(a.w);
    }
    __syncthreads();
    const int kl2 = (t & 7) * 8;
    #pragma unroll
    for (int i = 0; i < 2; i++) {
        const int nl2 = (t >> 3) + i * 32;
        short8 v;
        #pragma unroll
        for (int j = 0; j < 8; j++) v[j] = (short)Ls[kl2 + j][nl2];
        *(short8*)(out + (size_t)(n0 + nl2) * K + k0 + kl2) = v;
    }
}

// ---------------------------------------------------------------------------
// m97-style GEMM: C[M x N] = A[M][1024]bf16 * Bt[N][1024]bf16^T + bias(fp32)
// 128x128 tile, BK=32, 4 waves x 64x64 quadrant, global_load_lds staging.
// MODE 0 (N=3072): scatter bf16 -> Q[Z,H,N,64], K[Z,H,N,64], V^T[Z,H,64,N]
// MODE 1 (N=1024): fp32 store to outf.
// ---------------------------------------------------------------------------
template<int MODE>
__global__ __launch_bounds__(256)
void gemm_kernel(const unsigned short* __restrict__ A,
                 const unsigned short* __restrict__ Bt,
                 const float* __restrict__ bias,
                 unsigned short* __restrict__ out0,
                 unsigned short* __restrict__ out1,
                 unsigned short* __restrict__ out2,
                 float* __restrict__ outf)
{
    __shared__ __align__(16) unsigned short As[128][32];
    __shared__ __align__(16) unsigned short Bs[128][32];
    const int t    = threadIdx.x;
    const int m0   = blockIdx.x * 128, n0 = blockIdx.y * 128;
    const int lane = t & 63, wv = t >> 6;
    const int l15  = lane & 15, quad = lane >> 4;
    const int wm   = (wv >> 1) * 64, wn = (wv & 1) * 64;
    const int sr   = wv * 16 + (lane >> 2);     // staging row (0..63)
    const int sc   = (lane & 3) * 8;            // staging col (k)
    const unsigned short* Ag = A  + (size_t)m0 * 1024;
    const unsigned short* Bg = Bt + (size_t)n0 * 1024;

    f32x4 acc[4][4] = {};

    for (int kt = 0; kt < 1024; kt += 32) {
        __syncthreads();                        // prior iter's LDS reads done
        async_cp16(Ag + (size_t)(sr)      * 1024 + kt + sc, &As[sr][sc]);
        async_cp16(Ag + (size_t)(sr + 64) * 1024 + kt + sc, &As[sr + 64][sc]);
        async_cp16(Bg + (size_t)(sr)      * 1024 + kt + sc, &Bs[sr][sc]);
        async_cp16(Bg + (size_t)(sr + 64) * 1024 + kt + sc, &Bs[sr + 64][sc]);
        __syncthreads();                        // drains vmcnt (loads landed)

        bf16x8 af[4], bfr[4];
        #pragma unroll
        for (int mi = 0; mi < 4; mi++) af[mi]  = *(const bf16x8*)&As[wm + mi*16 + l15][quad*8];
        #pragma unroll
        for (int ni = 0; ni < 4; ni++) bfr[ni] = *(const bf16x8*)&Bs[wn + ni*16 + l15][quad*8];
        #pragma unroll
        for (int mi = 0; mi < 4; mi++)
            #pragma unroll
            for (int ni = 0; ni < 4; ni++)
                acc[mi][ni] = __builtin_amdgcn_mfma_f32_16x16x32_bf16(af[mi], bfr[ni], acc[mi][ni], 0, 0, 0);
    }

    #pragma unroll
    for (int mi = 0; mi < 4; mi++) {
        #pragma unroll
        for (int ni = 0; ni < 4; ni++) {
            const int col  = n0 + wn + ni*16 + l15;
            const float bval = bias[col];
            #pragma unroll
            for (int r = 0; r < 4; r++) {
                const int row = m0 + wm + mi*16 + quad*4 + r;
                const float val = acc[mi][ni][r] + bval;
                if (MODE == 0) {
                    const int which = col >> 10;          // 0=q 1=k 2=v
                    const int rem   = col & 1023;
                    const int h = rem >> 6, dd = rem & 63;
                    const int bb = row >> 12, ns = row & 4095;
                    if (which == 2) {
                        out2[((size_t)((bb * NH + h) * HD + dd)) * NSEQ + ns] = f2bf(val);
                    } else {
                        const size_t off = ((size_t)((bb * NH + h) * NSEQ + ns)) * HD + dd;
                        ((which == 0) ? out0 : out1)[off] = f2bf(val);
                    }
                } else {
                    outf[(size_t)row * 1024 + col] = val;
                }
            }
        }
    }
}

// ---------------------------------------------------------------------------
// Flash attention: block=(z,h,128 q-rows), 4 waves x 32 rows.
// Fixed-max softmax (M=8, exp2 domain) with FAST exp2 intrinsic; trunc-bf16 P;
// deferred l-reduction; P A-fragments explicitly hoisted. Output bf16.
// ---------------------------------------------------------------------------
#define C_LOG2E 0.1803368801111183f    // 0.125 * log2(e)
#define M_LOG2  11.541560327111707f    // 8 * log2(e)

__global__ __launch_bounds__(256, 4)
void attn_kernel(const unsigned short* __restrict__ qb,
                 const unsigned short* __restrict__ kb,
                 const unsigned short* __restrict__ vb,
                 unsigned short* __restrict__ ob)
{
    __shared__ __align__(16) unsigned short Ks[64][KPAD];
    __shared__ __align__(16) unsigned short Vt[64][KPAD];
    __shared__ __align__(16) unsigned short Ps[4][32][KPAD];

    const int t    = threadIdx.x;
    const int wv   = t >> 6, lane = t & 63, l15 = lane & 15, quad = lane >> 4;
    const int q0   = blockIdx.x * 128;
    const int h    = blockIdx.y, b = blockIdx.z;
    const size_t bh = (size_t)(b * NH + h) * NSEQ * HD;
    const unsigned short* Qp  = qb + bh;
    const unsigned short* Kp  = kb + bh;
    const unsigned short* Vtp = vb + bh;

    bf16x8 aq[2][2];
    #pragma unroll
    for (int mi = 0; mi < 2; mi++) {
        const unsigned short* qrow =
            Qp + (size_t)(q0 + wv*32 + mi*16 + l15) * HD + quad*8;
        aq[mi][0] = *(const bf16x8*)(qrow);
        aq[mi][1] = *(const bf16x8*)(qrow + 32);
    }

    float l_loc[2][4] = {};
    f32x4 acc_o[2][4] = {};

    const int sr = t >> 2, sc = (t & 3) * 16;

    for (int kt = 0; kt < NSEQ; kt += 64) {
        short8 kv0 = *(const short8*)(Kp  + (size_t)(kt + sr) * HD + sc);
        short8 kv1 = *(const short8*)(Kp  + (size_t)(kt + sr) * HD + sc + 8);
        short8 vv0 = *(const short8*)(Vtp + (size_t)sr * NSEQ + kt + sc);
        short8 vv1 = *(const short8*)(Vtp + (size_t)sr * NSEQ + kt + sc + 8);
        __syncthreads();
        *(short8*)&Ks[sr][sc]     = kv0;
        *(short8*)&Ks[sr][sc + 8] = kv1;
        *(short8*)&Vt[sr][sc]     = vv0;
        *(short8*)&Vt[sr][sc + 8] = vv1;
        __syncthreads();

        // S = Q K^T : 32 q-rows x 64 keys per wave
        f32x4 accs[2][4] = {};
        #pragma unroll
        for (int nj = 0; nj < 4; nj++) {
            bf16x8 bk0 = *(const bf16x8*)&Ks[nj*16 + l15][quad*8];
            bf16x8 bk1 = *(const bf16x8*)&Ks[nj*16 + l15][32 + quad*8];
            #pragma unroll
            for (int mi = 0; mi < 2; mi++) {
                accs[mi][nj] = __builtin_amdgcn_mfma_f32_16x16x32_bf16(aq[mi][0], bk0, accs[mi][nj], 0, 0, 0);
                accs[mi][nj] = __builtin_amdgcn_mfma_f32_16x16x32_bf16(aq[mi][1], bk1, accs[mi][nj], 0, 0, 0);
            }
        }

        // fixed-max softmax: p = 2^(s*c - M), single v_exp_f32 per score
        #pragma unroll
        for (int mi = 0; mi < 2; mi++) {
            #pragma unroll
            for (int r = 0; r < 4; r++) {
                const int prow = mi*16 + quad*4 + r;
                float lsum = 0.f;
                #pragma unroll
                for (int nj = 0; nj < 4; nj++) {
                    const float p = FAST_EXP2(fmaf(accs[mi][nj][r], C_LOG2E, -M_LOG2));
                    const unsigned int pb = __float_as_uint(p);
                    Ps[wv][prow][nj*16 + l15] = (unsigned short)(pb >> 16);
                    lsum += __uint_as_float(pb & 0xffff0000u);
                }
                l_loc[mi][r] += lsum;
            }
        }
        // Ps wave-private: within-wave ds ordering via lgkmcnt, no barrier.

        // O += P V  (P fragments hoisted out of the nj loop)
        bf16x8 ap[2][2];
        #pragma unroll
        for (int mi = 0; mi < 2; mi++) {
            ap[mi][0] = *(const bf16x8*)&Ps[wv][mi*16 + l15][quad*8];
            ap[mi][1] = *(const bf16x8*)&Ps[wv][mi*16 + l15][32 + quad*8];
        }
        #pragma unroll
        for (int nj = 0; nj < 4; nj++) {
            bf16x8 bv0 = *(const bf16x8*)&Vt[nj*16 + l15][quad*8];
            bf16x8 bv1 = *(const bf16x8*)&Vt[nj*16 + l15][32 + quad*8];
            #pragma unroll
            for (int mi = 0; mi < 2; mi++) {
                acc_o[mi][nj] = __builtin_amdgcn_mfma_f32_16x16x32_bf16(ap[mi][0], bv0, acc_o[mi][nj], 0, 0, 0);
                acc_o[mi][nj] = __builtin_amdgcn_mfma_f32_16x16x32_bf16(ap[mi][1], bv1, acc_o[mi][nj], 0, 0, 0);
            }
        }
    }

    #pragma unroll
    for (int mi = 0; mi < 2; mi++) {
        #pragma unroll
        for (int r = 0; r < 4; r++) {
            float l = l_loc[mi][r];
            #pragma unroll
            for (int off = 1; off < 16; off <<= 1) l += __shfl_xor(l, off);
            const float inv = 1.0f / l;
            const int row = q0 + wv*32 + mi*16 + quad*4 + r;
            const size_t base = ((size_t)(b * NSEQ + row)) * DIM + h * HD;
            #pragma unroll
            for (int nj = 0; nj < 4; nj++)
                ob[base + nj*16 + l15] = f2bf(acc_o[mi][nj][r] * inv);
        }
    }
}

extern "C" void kernel_launch(void* const* d_in, const int* in_sizes, int n_in,
                              void* d_out, int out_size, void* d_ws, size_t ws_size,
                              hipStream_t stream)
{
    const float *x = nullptr, *w_qkv = nullptr, *b_qkv = nullptr,
                *w_o = nullptr, *b_o = nullptr;
    for (int i = 0; i < n_in; i++) {
        switch (in_sizes[i]) {
            case 8388608: x     = (const float*)d_in[i]; break;
            case 3145728: w_qkv = (const float*)d_in[i]; break;
            case 3072:    b_qkv = (const float*)d_in[i]; break;
            case 1048576: w_o   = (const float*)d_in[i]; break;
            case 1024:    b_o   = (const float*)d_in[i]; break;
        }
    }
    float* out = (float*)d_out;                     // [2,4096,1024] fp32

    const size_t WQB  = (size_t)3072 * 1024;        // elems
    const size_t WOB  = (size_t)1024 * 1024;
    const size_t SEGB = (size_t)NSEQ * DIM;         // 4,194,304 elems / batch

    char* p = (char*)d_ws;
    unsigned short* wqb = (unsigned short*)p;  p += WQB * 2;
    unsigned short* wob = (unsigned short*)p;  p += WOB * 2;

    transpose_conv_kernel<3072, 1024><<<dim3(16, 48), 256, 0, stream>>>(w_qkv, wqb);
    transpose_conv_kernel<1024, 1024><<<dim3(16, 16), 256, 0, stream>>>(w_o, wob);

    const size_t tier1_bytes = (WQB + WOB + 2*SEGB + 3*2*SEGB) * 2;  // 75.5 MB
    if (ws_size >= tier1_bytes) {
        unsigned short* xb = (unsigned short*)p;  p += 2 * SEGB * 2;
        unsigned short* qb = (unsigned short*)p;  p += 2 * SEGB * 2;
        unsigned short* kb = (unsigned short*)p;  p += 2 * SEGB * 2;
        unsigned short* vb = (unsigned short*)p;
        unsigned short* ao = xb;                  // xb dead after GEMM1
        conv_kernel<<<4096, 256, 0, stream>>>(x, xb);
        gemm_kernel<0><<<dim3(64, 24), 256, 0, stream>>>(xb, wqb, b_qkv, qb, kb, vb, nullptr);
        attn_kernel<<<dim3(32, NH, 2), 256, 0, stream>>>(qb, kb, vb, ao);
        gemm_kernel<1><<<dim3(64, 8), 256, 0, stream>>>(ao, wob, b_o, nullptr, nullptr, nullptr, out);
    } else {
        // per-batch: peak 41.9 MB
        unsigned short* xb = (unsigned short*)p;  p += SEGB * 2;
        unsigned short* qb = (unsigned short*)p;  p += SEGB * 2;
        unsigned short* kb = (unsigned short*)p;  p += SEGB * 2;
        unsigned short* vb = (unsigned short*)p;
        unsigned short* ao = xb;
        for (int b = 0; b < 2; b++) {
            conv_kernel<<<2048, 256, 0, stream>>>(x + b * SEGB, xb);
            gemm_kernel<0><<<dim3(32, 24), 256, 0, stream>>>(xb, wqb, b_qkv, qb, kb, vb, nullptr);
            attn_kernel<<<dim3(32, NH, 1), 256, 0, stream>>>(qb, kb, vb, ao);
            gemm_kernel<1><<<dim3(32, 8), 256, 0, stream>>>(ao, wob, b_o, nullptr, nullptr, nullptr, out + b * SEGB);
        }
    }
}